// Round 1
// baseline (3037.376 us; speedup 1.0000x reference)
//
#include <hip/hip_runtime.h>
#include <cmath>

#define HH 192
#define WW 192
#define HWSZ (192*192)
#define NB 8
#define NCQ 128
#define NCV 64

// ---------------------------------------------------------------------------
// K1: fused conv3x3(q, {ow1|ww1}) + bias + exact gelu -> t1 [B][128][H][W]
//     channels 0..63  = gelu(conv(q, ow1)+ob1)   (offsets branch input)
//     channels 64..127= gelu(conv(q, ww1)+wb1)   (weights branch input)
// grid: x = 36 tiles (6x6 of 32x32 px), y = B, z = 8 oc-chunks of 16
// block: 256 threads = 16x16, each thread computes 2x2 px for 16 oc.
// ---------------------------------------------------------------------------
__global__ __launch_bounds__(256) void k1_conv1(
    const float* __restrict__ q,
    const float* __restrict__ ow1, const float* __restrict__ ob1,
    const float* __restrict__ ww1, const float* __restrict__ wb1,
    float* __restrict__ t1)
{
    __shared__ float lds[8 * 34 * 36];          // 8 cin planes, 34 rows, stride 36
    const int tid = threadIdx.x;
    const int b   = blockIdx.y;
    const int ocb = blockIdx.z << 4;            // 0,16,...,112 (never straddles 64)
    const int ty0 = (blockIdx.x / 6) << 5;
    const int tx0 = (blockIdx.x % 6) << 5;

    const float* wsrc = (ocb < 64) ? (ow1 + ocb * NCQ * 9) : (ww1 + (ocb - 64) * NCQ * 9);
    const float* bsrc = (ocb < 64) ? (ob1 + ocb) : (wb1 + (ocb - 64));

    // staging precompute: 34*34 = 1156 halo elements, 5 slots/thread
    int  sgoff[5], slds[5];
    bool swr[5], sok[5];
#pragma unroll
    for (int j = 0; j < 5; ++j) {
        const int i = tid + j * 256;
        const int r = i / 34;
        const int c = i - r * 34;
        const int gy = ty0 - 1 + r;
        const int gx = tx0 - 1 + c;
        swr[j]   = (i < 1156);
        sok[j]   = swr[j] && (gy >= 0) && (gy < HH) && (gx >= 0) && (gx < WW);
        sgoff[j] = gy * WW + gx;
        slds[j]  = r * 36 + c;
    }
    const float* qb = q + (size_t)b * NCQ * HWSZ;

    float acc[16][2][2];
#pragma unroll
    for (int oc = 0; oc < 16; ++oc)
#pragma unroll
        for (int r = 0; r < 2; ++r)
#pragma unroll
            for (int c = 0; c < 2; ++c) acc[oc][r][c] = 0.f;

    const int ty = (tid >> 4) << 1;
    const int tx = (tid & 15) << 1;

    for (int cb = 0; cb < NCQ; cb += 8) {
        __syncthreads();
#pragma unroll
        for (int p = 0; p < 8; ++p) {
            const float* qp = qb + (size_t)(cb + p) * HWSZ;
#pragma unroll
            for (int j = 0; j < 5; ++j) {
                if (swr[j]) lds[p * 1224 + slds[j]] = sok[j] ? qp[sgoff[j]] : 0.f;
            }
        }
        __syncthreads();
#pragma unroll
        for (int p = 0; p < 8; ++p) {
            float win[4][4];
#pragma unroll
            for (int r = 0; r < 4; ++r)
#pragma unroll
                for (int c = 0; c < 4; ++c)
                    win[r][c] = lds[p * 1224 + (ty + r) * 36 + (tx + c)];
            const float* wp = wsrc + (cb + p) * 9;      // wave-uniform -> s_load
#pragma unroll
            for (int oc = 0; oc < 16; ++oc) {
                const float* wo = wp + oc * (NCQ * 9);
#pragma unroll
                for (int t = 0; t < 9; ++t) {
                    const int dy = t / 3, dx = t % 3;
                    const float wv = wo[t];
                    acc[oc][0][0] = fmaf(wv, win[dy][dx],       acc[oc][0][0]);
                    acc[oc][0][1] = fmaf(wv, win[dy][dx + 1],   acc[oc][0][1]);
                    acc[oc][1][0] = fmaf(wv, win[dy + 1][dx],   acc[oc][1][0]);
                    acc[oc][1][1] = fmaf(wv, win[dy + 1][dx + 1], acc[oc][1][1]);
                }
            }
        }
    }

#pragma unroll
    for (int oc = 0; oc < 16; ++oc) {
        const float bias = bsrc[oc];
#pragma unroll
        for (int pr = 0; pr < 2; ++pr)
#pragma unroll
            for (int pc = 0; pc < 2; ++pc) {
                const float x = acc[oc][pr][pc] + bias;
                const float g = 0.5f * x * (1.0f + erff(x * 0.70710678118654752f));
                t1[(((size_t)b * NCQ + ocb + oc) * HH + (ty0 + ty + pr)) * WW
                   + (tx0 + tx + pc)] = g;
            }
    }
}

// ---------------------------------------------------------------------------
// K2: conv2 (12 out ch) + bias + softmax + bilinear gather + weighted sum
// grid: x = 144 tiles (12x12 of 16x16 px), y = B; block 256, 1 px/thread.
// ---------------------------------------------------------------------------
__global__ __launch_bounds__(256) void k2_rest(
    const float* __restrict__ t1, const float* __restrict__ v,
    const float* __restrict__ ow2, const float* __restrict__ ob2,
    const float* __restrict__ ww2, const float* __restrict__ wb2,
    float* __restrict__ out)
{
    __shared__ float lds[16 * 360];             // 16 planes (8 off-in + 8 wt-in), 18x20
    const int tid = threadIdx.x;
    const int b   = blockIdx.y;
    const int ty0 = (blockIdx.x / 12) << 4;
    const int tx0 = (blockIdx.x % 12) << 4;

    int  sgoff[2], slds[2];
    bool swr[2], sok[2];
#pragma unroll
    for (int j = 0; j < 2; ++j) {
        const int i = tid + j * 256;
        const int r = i / 18;
        const int c = i - r * 18;
        const int gy = ty0 - 1 + r;
        const int gx = tx0 - 1 + c;
        swr[j]   = (i < 324);
        sok[j]   = swr[j] && (gy >= 0) && (gy < HH) && (gx >= 0) && (gx < WW);
        sgoff[j] = gy * WW + gx;
        slds[j]  = r * 20 + c;
    }
    const float* tb = t1 + (size_t)b * NCQ * HWSZ;

    float acc[12];
#pragma unroll
    for (int i = 0; i < 12; ++i) acc[i] = 0.f;

    const int ty = tid >> 4, tx = tid & 15;

    for (int cb = 0; cb < 64; cb += 8) {
        __syncthreads();
#pragma unroll
        for (int p = 0; p < 16; ++p) {
            const int ch = (p < 8) ? (cb + p) : (64 + cb + (p - 8));
            const float* tp = tb + (size_t)ch * HWSZ;
#pragma unroll
            for (int j = 0; j < 2; ++j)
                if (swr[j]) lds[p * 360 + slds[j]] = sok[j] ? tp[sgoff[j]] : 0.f;
        }
        __syncthreads();
#pragma unroll
        for (int p = 0; p < 8; ++p) {
            float win[3][3];
#pragma unroll
            for (int r = 0; r < 3; ++r)
#pragma unroll
                for (int c = 0; c < 3; ++c)
                    win[r][c] = lds[p * 360 + (ty + r) * 20 + (tx + c)];
            const float* wo = ow2 + (cb + p) * 9;       // uniform -> s_load
#pragma unroll
            for (int oc = 0; oc < 8; ++oc)
#pragma unroll
                for (int t = 0; t < 9; ++t)
                    acc[oc] = fmaf(wo[oc * 576 + t], win[t / 3][t % 3], acc[oc]);

            float win2[3][3];
#pragma unroll
            for (int r = 0; r < 3; ++r)
#pragma unroll
                for (int c = 0; c < 3; ++c)
                    win2[r][c] = lds[(p + 8) * 360 + (ty + r) * 20 + (tx + c)];
            const float* wl = ww2 + (cb + p) * 9;
#pragma unroll
            for (int oc = 0; oc < 4; ++oc)
#pragma unroll
                for (int t = 0; t < 9; ++t)
                    acc[8 + oc] = fmaf(wl[oc * 576 + t], win2[t / 3][t % 3], acc[8 + oc]);
        }
    }

    const int y = ty0 + ty, x = tx0 + tx;

    float offv[8];
#pragma unroll
    for (int i = 0; i < 8; ++i) offv[i] = acc[i] + ob2[i];
    float lg[4];
#pragma unroll
    for (int i = 0; i < 4; ++i) lg[i] = acc[8 + i] + wb2[i];

    const float m = fmaxf(fmaxf(lg[0], lg[1]), fmaxf(lg[2], lg[3]));
    float e[4], s = 0.f;
#pragma unroll
    for (int i = 0; i < 4; ++i) { e[i] = expf(lg[i] - m); s += e[i]; }
    const float sinv = 1.f / s;
    float wk[4];
#pragma unroll
    for (int i = 0; i < 4; ++i) wk[i] = e[i] * sinv;

    float cw[16];
    int   cidx[16];
#pragma unroll
    for (int k = 0; k < 4; ++k) {
        const float px = (float)x + offv[2 * k]     * (0.5f * (WW - 1));
        const float py = (float)y + offv[2 * k + 1] * (0.5f * (HH - 1));
        const float fx0 = floorf(px), fy0 = floorf(py);
        const float wx1 = px - fx0, wx0f = 1.f - wx1;
        const float wy1 = py - fy0, wy0f = 1.f - wy1;
#pragma unroll
        for (int cy = 0; cy < 2; ++cy)
#pragma unroll
            for (int cx = 0; cx < 2; ++cx) {
                const float fx = fx0 + (float)cx;
                const float fy = fy0 + (float)cy;
                const bool ok = (fx >= 0.f) && (fx <= (float)(WW - 1)) &&
                                (fy >= 0.f) && (fy <= (float)(HH - 1));
                const int xi = (int)fminf(fmaxf(fx, 0.f), (float)(WW - 1));
                const int yi = (int)fminf(fmaxf(fy, 0.f), (float)(HH - 1));
                const float wgt = (cx ? wx1 : wx0f) * (cy ? wy1 : wy0f) * wk[k];
                cidx[k * 4 + cy * 2 + cx] = yi * WW + xi;
                cw[k * 4 + cy * 2 + cx]   = ok ? wgt : 0.f;
            }
    }

    const float* vb = v + (size_t)b * NCV * HWSZ;
    float* ob = out + (size_t)b * NCV * HWSZ + (size_t)(y * WW + x);
#pragma unroll 4
    for (int c = 0; c < NCV; ++c) {
        const float* vp = vb + (size_t)c * HWSZ;
        float sacc = 0.f;
#pragma unroll
        for (int i = 0; i < 16; ++i) sacc = fmaf(cw[i], vp[cidx[i]], sacc);
        ob[(size_t)c * HWSZ] = sacc;
    }
}

extern "C" void kernel_launch(void* const* d_in, const int* in_sizes, int n_in,
                              void* d_out, int out_size, void* d_ws, size_t ws_size,
                              hipStream_t stream) {
    const float* q   = (const float*)d_in[0];
    const float* v   = (const float*)d_in[1];
    const float* ow1 = (const float*)d_in[2];
    const float* ob1 = (const float*)d_in[3];
    const float* ow2 = (const float*)d_in[4];
    const float* ob2 = (const float*)d_in[5];
    const float* ww1 = (const float*)d_in[6];
    const float* wb1 = (const float*)d_in[7];
    const float* ww2 = (const float*)d_in[8];
    const float* wb2 = (const float*)d_in[9];

    float* t1  = (float*)d_ws;                  // needs 8*128*192*192*4 = 151 MB
    float* out = (float*)d_out;

    dim3 g1(36, 8, 8);
    k1_conv1<<<g1, dim3(256), 0, stream>>>(q, ow1, ob1, ww1, wb1, t1);
    dim3 g2(144, 8);
    k2_rest<<<g2, dim3(256), 0, stream>>>(t1, v, ow2, ob2, ww2, wb2, out);
}

// Round 3
// 1744.555 us; speedup vs baseline: 1.7411x; 1.7411x over previous
//
#include <hip/hip_runtime.h>
#include <hip/hip_bf16.h>
#include <cmath>

#define HH 192
#define WW 192
#define HWSZ (192*192)
#define NCQ 128
#define NCV 64
#define PP 194          // padded spatial dim (1-px zero border)

typedef __attribute__((ext_vector_type(8))) short short8;
typedef __attribute__((ext_vector_type(4))) float f32x4;

__device__ inline uint16_t f2bf(float x){ __hip_bfloat16 h = __float2bfloat16(x); return *(uint16_t*)&h; }
__device__ inline float bf2f(uint16_t u){ return __uint_as_float(((uint32_t)u)<<16); }

// ---------------------------------------------------------------------------
// K0z: zero the 1-px borders of the padded qhi/qlo planes
// ---------------------------------------------------------------------------
__global__ __launch_bounds__(256) void k0z(uint16_t* __restrict__ qhi, uint16_t* __restrict__ qlo){
    int bi = blockIdx.x; int b = bi / PP; int yP = bi - b * PP;
    size_t rowbase = (((size_t)b * PP + yP) * PP) * NCQ;       // u16 index
    uint32_t* h32 = (uint32_t*)(qhi + rowbase);
    uint32_t* l32 = (uint32_t*)(qlo + rowbase);
    if (yP == 0 || yP == PP-1){
        for (int i = threadIdx.x; i < PP*NCQ/2; i += 256){ h32[i] = 0; l32[i] = 0; }
    } else {
        if (threadIdx.x < 64){ h32[threadIdx.x] = 0; l32[threadIdx.x] = 0; }
        else if (threadIdx.x < 128){ int i = (PP-1)*64 + threadIdx.x - 64; h32[i] = 0; l32[i] = 0; }
    }
}

// ---------------------------------------------------------------------------
// K0w: split conv1 weights to bf16 hi/lo, layout [m 128][tap 9][ic 128]
//      m<64 -> ow1 branch, m>=64 -> ww1 branch
// ---------------------------------------------------------------------------
__global__ __launch_bounds__(256) void k0w(const float* __restrict__ ow1, const float* __restrict__ ww1,
                                           uint16_t* __restrict__ whi, uint16_t* __restrict__ wlo){
    int d = blockIdx.x * 256 + threadIdx.x;
    if (d >= 128 * 1152) return;
    int m = d / 1152; int r = d - m * 1152; int tap = r >> 7; int ic = r & 127;
    float wv = (m < 64) ? ow1[((size_t)m * NCQ + ic) * 9 + tap]
                        : ww1[((size_t)(m - 64) * NCQ + ic) * 9 + tap];
    uint16_t hi = f2bf(wv);
    uint16_t lo = f2bf(wv - bf2f(hi));
    whi[d] = hi; wlo[d] = lo;
}

// ---------------------------------------------------------------------------
// K0q: q [b][ic][y][x] fp32 -> padded channels-last bf16 hi/lo planes
//      qhi/qlo [b][yP 194][xP 194][ic 128]
// grid (3, 192, 8): x-chunk 64, y, b
// ---------------------------------------------------------------------------
__global__ __launch_bounds__(256) void k0q(const float* __restrict__ q,
                                           uint16_t* __restrict__ qhi, uint16_t* __restrict__ qlo){
    __shared__ uint16_t lh[64 * 136], ll[64 * 136];
    const int x0 = blockIdx.x * 64, y = blockIdx.y, b = blockIdx.z;
    const int t = threadIdx.x;
    const int xr = t & 63;
#pragma unroll 4
    for (int it = 0; it < 32; ++it){
        int ic = it * 4 + (t >> 6);
        float val = q[(((size_t)b * NCQ + ic) * HH + y) * WW + x0 + xr];
        uint16_t hi = f2bf(val);
        uint16_t lo = f2bf(val - bf2f(hi));
        lh[xr * 136 + ic] = hi;
        ll[xr * 136 + ic] = lo;
    }
    __syncthreads();
#pragma unroll
    for (int it = 0; it < 4; ++it){
        int s = t + it * 256;             // 1024 slots: 64 x * 16 ic-chunks
        int x = s >> 4, icb = (s & 15) * 8;
        size_t dst = (((size_t)b * PP + y + 1) * PP + (x0 + x + 1)) * NCQ + icb;
        *(int4*)(qhi + dst) = *(const int4*)(lh + x * 136 + icb);
        *(int4*)(qlo + dst) = *(const int4*)(ll + x * 136 + icb);
    }
}

// ---------------------------------------------------------------------------
// K1: conv1 (both branches, M=128) via split-precision bf16 MFMA + gelu -> t1
// grid (576, 8): blockIdx.x = y*3 + strip... (strip = bx%3, y = bx/3); 256 thr
// 4 waves: wave tile 64 oc x 32 px; block tile 128 oc x 64 px (one row strip)
// ---------------------------------------------------------------------------
__global__ __launch_bounds__(256) void k1_conv1_mfma(
    const uint16_t* __restrict__ qhi, const uint16_t* __restrict__ qlo,
    const uint16_t* __restrict__ whi, const uint16_t* __restrict__ wlo,
    const float* __restrict__ ob1, const float* __restrict__ wb1,
    float* __restrict__ t1)
{
    __shared__ uint16_t qlds[2 * 6336];   // hi plane [r3][c66][ic32], then lo plane
    const int tid = threadIdx.x;
    const int b = blockIdx.y;
    const int strip = blockIdx.x % 3;
    const int y = blockIdx.x / 3;
    const int x0 = strip * 64;
    const int lane = tid & 63;
    const int wid = tid >> 6;
    const int wm = wid >> 1;              // oc half (0..1)
    const int wn = wid & 1;               // px half (0..1)
    const int l15 = lane & 15;
    const int g = lane >> 4;

    // staging slot precompute: 1584 16B-slots (hi 792 + lo 792), 7 per thread
    const uint16_t* ssrc[7]; int slds[7]; bool sok[7];
#pragma unroll
    for (int j = 0; j < 7; ++j){
        int s = tid + j * 256;
        sok[j] = (s < 1584);
        int p = (s >= 792) ? 1 : 0;
        int s7 = s - p * 792;
        int r = s7 / 264;                 // 264 = 66 c * 4 (16B chunks of 32 ic)
        int tt = s7 - r * 264;
        int c = tt >> 2;
        int t3 = tt & 3;
        const uint16_t* base = p ? qlo : qhi;
        ssrc[j] = base + (((size_t)b * PP + y + r) * PP + (x0 + c)) * NCQ + t3 * 8;
        slds[j] = p * 6336 + s7 * 8;
    }

    f32x4 acc[4][2];
#pragma unroll
    for (int mf = 0; mf < 4; ++mf)
#pragma unroll
        for (int nf = 0; nf < 2; ++nf) acc[mf][nf] = (f32x4){0.f,0.f,0.f,0.f};

    // prologue loads for kc=0
    float4 sreg[7];
#pragma unroll
    for (int j = 0; j < 7; ++j) if (sok[j]) sreg[j] = *(const float4*)(ssrc[j]);

    for (int kc = 0; kc < 4; ++kc){
        __syncthreads();                  // previous compute done with LDS
#pragma unroll
        for (int j = 0; j < 7; ++j) if (sok[j]) *(float4*)(&qlds[slds[j]]) = sreg[j];
        __syncthreads();
        if (kc < 3){
#pragma unroll
            for (int j = 0; j < 7; ++j) if (sok[j]) sreg[j] = *(const float4*)(ssrc[j] + (kc + 1) * 32);
        }
        const int kb = kc * 32;
#pragma unroll
        for (int dy = 0; dy < 3; ++dy)
#pragma unroll
        for (int dx = 0; dx < 3; ++dx){
            const int tap = dy * 3 + dx;
            short8 bh[2], bl[2];
#pragma unroll
            for (int nf = 0; nf < 2; ++nf){
                int c = wn * 32 + nf * 16 + l15 + dx;
                int off = (dy * 66 + c) * 32 + 8 * g;
                bh[nf] = *(const short8*)(&qlds[off]);
                bl[nf] = *(const short8*)(&qlds[6336 + off]);
            }
#pragma unroll
            for (int mf = 0; mf < 4; ++mf){
                size_t wo = (size_t)((wm * 64 + mf * 16 + l15) * 9 + tap) * 128 + kb + 8 * g;
                short8 ah = *(const short8*)(whi + wo);
                short8 al = *(const short8*)(wlo + wo);
#pragma unroll
                for (int nf = 0; nf < 2; ++nf){
                    acc[mf][nf] = __builtin_amdgcn_mfma_f32_16x16x32_bf16(ah, bh[nf], acc[mf][nf], 0, 0, 0);
                    acc[mf][nf] = __builtin_amdgcn_mfma_f32_16x16x32_bf16(ah, bl[nf], acc[mf][nf], 0, 0, 0);
                    acc[mf][nf] = __builtin_amdgcn_mfma_f32_16x16x32_bf16(al, bh[nf], acc[mf][nf], 0, 0, 0);
                }
            }
        }
    }

    // epilogue: bias + exact gelu + store
    const float* bias = wm ? wb1 : ob1;
#pragma unroll
    for (int mf = 0; mf < 4; ++mf){
#pragma unroll
        for (int nf = 0; nf < 2; ++nf){
#pragma unroll
            for (int qq = 0; qq < 4; ++qq){
                int ocl = mf * 16 + g * 4 + qq;
                float xv = acc[mf][nf][qq] + bias[ocl];
                float ge = 0.5f * xv * (1.0f + erff(xv * 0.70710678118654752f));
                int oc = wm * 64 + ocl;
                int x = x0 + wn * 32 + nf * 16 + l15;
                t1[(((size_t)b * NCQ + oc) * HH + y) * WW + x] = ge;
            }
        }
    }
}

// ---------------------------------------------------------------------------
// K2b: v [b][c][y][x] fp32 -> vcl [b][y][x][c] bf16 (channels-last)
// grid (3, 192, 8)
// ---------------------------------------------------------------------------
__global__ __launch_bounds__(256) void k2b_vcl(const float* __restrict__ v, uint16_t* __restrict__ vcl){
    __shared__ uint16_t tl[64 * 72];
    const int x0 = blockIdx.x * 64, y = blockIdx.y, b = blockIdx.z;
    const int t = threadIdx.x;
    const int xr = t & 63;
#pragma unroll 4
    for (int it = 0; it < 16; ++it){
        int c = it * 4 + (t >> 6);
        float val = v[(((size_t)b * NCV + c) * HH + y) * WW + x0 + xr];
        tl[xr * 72 + c] = f2bf(val);
    }
    __syncthreads();
#pragma unroll
    for (int it = 0; it < 2; ++it){
        int s = t + it * 256;             // 512 slots: 64 x * 8 c-chunks
        int x = s >> 3, cb = (s & 7) * 8;
        size_t dst = ((size_t)b * HWSZ + (size_t)y * WW + x0 + x) * NCV + cb;
        *(int4*)(vcl + dst) = *(const int4*)(tl + x * 72 + cb);
    }
}

// ---------------------------------------------------------------------------
// K2a: conv2 (12 out ch) + bias + softmax + sample-coeff prep -> sparm
// grid (144, 8), block 256, 1 px/thread (16x16 tiles)
// ---------------------------------------------------------------------------
__global__ __launch_bounds__(256) void k2a_prep(
    const float* __restrict__ t1,
    const float* __restrict__ ow2, const float* __restrict__ ob2,
    const float* __restrict__ ww2, const float* __restrict__ wb2,
    float2* __restrict__ sparm)
{
    __shared__ float lds[16 * 360];
    const int tid = threadIdx.x;
    const int b   = blockIdx.y;
    const int ty0 = (blockIdx.x / 12) << 4;
    const int tx0 = (blockIdx.x % 12) << 4;

    int  sgoff[2], slds2[2];
    bool swr[2], sok2[2];
#pragma unroll
    for (int j = 0; j < 2; ++j){
        const int i = tid + j * 256;
        const int r = i / 18;
        const int c = i - r * 18;
        const int gy = ty0 - 1 + r;
        const int gx = tx0 - 1 + c;
        swr[j]   = (i < 324);
        sok2[j]  = swr[j] && (gy >= 0) && (gy < HH) && (gx >= 0) && (gx < WW);
        sgoff[j] = gy * WW + gx;
        slds2[j] = r * 20 + c;
    }
    const float* tb = t1 + (size_t)b * NCQ * HWSZ;

    float acc[12];
#pragma unroll
    for (int i = 0; i < 12; ++i) acc[i] = 0.f;

    const int ty = tid >> 4, tx = tid & 15;

    for (int cb = 0; cb < 64; cb += 8){
        __syncthreads();
#pragma unroll
        for (int p = 0; p < 16; ++p){
            const int ch = (p < 8) ? (cb + p) : (64 + cb + (p - 8));
            const float* tp = tb + (size_t)ch * HWSZ;
#pragma unroll
            for (int j = 0; j < 2; ++j)
                if (swr[j]) lds[p * 360 + slds2[j]] = sok2[j] ? tp[sgoff[j]] : 0.f;
        }
        __syncthreads();
#pragma unroll
        for (int p = 0; p < 8; ++p){
            float win[3][3];
#pragma unroll
            for (int r = 0; r < 3; ++r)
#pragma unroll
                for (int c = 0; c < 3; ++c)
                    win[r][c] = lds[p * 360 + (ty + r) * 20 + (tx + c)];
            const float* wo = ow2 + (cb + p) * 9;
#pragma unroll
            for (int oc = 0; oc < 8; ++oc)
#pragma unroll
                for (int t = 0; t < 9; ++t)
                    acc[oc] = fmaf(wo[oc * 576 + t], win[t / 3][t % 3], acc[oc]);

            float win2[3][3];
#pragma unroll
            for (int r = 0; r < 3; ++r)
#pragma unroll
                for (int c = 0; c < 3; ++c)
                    win2[r][c] = lds[(p + 8) * 360 + (ty + r) * 20 + (tx + c)];
            const float* wl = ww2 + (cb + p) * 9;
#pragma unroll
            for (int oc = 0; oc < 4; ++oc)
#pragma unroll
                for (int t = 0; t < 9; ++t)
                    acc[8 + oc] = fmaf(wl[oc * 576 + t], win2[t / 3][t % 3], acc[8 + oc]);
        }
    }

    const int y = ty0 + ty, x = tx0 + tx;

    float offv[8];
#pragma unroll
    for (int i = 0; i < 8; ++i) offv[i] = acc[i] + ob2[i];
    float lg[4];
#pragma unroll
    for (int i = 0; i < 4; ++i) lg[i] = acc[8 + i] + wb2[i];

    const float m = fmaxf(fmaxf(lg[0], lg[1]), fmaxf(lg[2], lg[3]));
    float e[4], s = 0.f;
#pragma unroll
    for (int i = 0; i < 4; ++i){ e[i] = expf(lg[i] - m); s += e[i]; }
    const float sinv = 1.f / s;

    float2 pr[16];
#pragma unroll
    for (int k = 0; k < 4; ++k){
        const float wk = e[k] * sinv;
        const float px = (float)x + offv[2 * k]     * (0.5f * (WW - 1));
        const float py = (float)y + offv[2 * k + 1] * (0.5f * (HH - 1));
        const float fx0 = floorf(px), fy0 = floorf(py);
        const float wx1 = px - fx0, wx0f = 1.f - wx1;
        const float wy1 = py - fy0, wy0f = 1.f - wy1;
#pragma unroll
        for (int cy = 0; cy < 2; ++cy)
#pragma unroll
            for (int cx = 0; cx < 2; ++cx){
                const float fx = fx0 + (float)cx;
                const float fy = fy0 + (float)cy;
                const bool ok = (fx >= 0.f) && (fx <= (float)(WW - 1)) &&
                                (fy >= 0.f) && (fy <= (float)(HH - 1));
                const int xi = (int)fminf(fmaxf(fx, 0.f), (float)(WW - 1));
                const int yi = (int)fminf(fmaxf(fy, 0.f), (float)(HH - 1));
                const float wgt = (cx ? wx1 : wx0f) * (cy ? wy1 : wy0f) * wk;
                pr[k * 4 + cy * 2 + cx] = make_float2(ok ? wgt : 0.f,
                                                      __int_as_float(yi * WW + xi));
            }
    }
    float2* sp = sparm + ((size_t)b * HWSZ + (size_t)y * WW + x) * 16;
#pragma unroll
    for (int i = 0; i < 16; ++i) sp[i] = pr[i];
}

// ---------------------------------------------------------------------------
// K3: gather + weighted sum. 1 wave per pixel (lane = channel), 16 px/block.
// grid 18432, block 1024
// ---------------------------------------------------------------------------
__global__ __launch_bounds__(1024) void k3_gather(
    const float2* __restrict__ sparm, const uint16_t* __restrict__ vcl,
    float* __restrict__ out)
{
    const int tid = threadIdx.x;
    const int wid = tid >> 6, lane = tid & 63;
    const int p = blockIdx.x * 16 + wid;
    const int b = p / HWSZ;
    const int hw = p - b * HWSZ;
    (void)hw;

    const float4* s4 = (const float4*)(sparm + (size_t)p * 16);
    float4 f[8];
#pragma unroll
    for (int i = 0; i < 8; ++i) f[i] = s4[i];

    const uint16_t* vb = vcl + (size_t)b * HWSZ * NCV + lane;
    float acc = 0.f;
#pragma unroll
    for (int i = 0; i < 8; ++i){
        int i0 = __float_as_int(f[i].y);
        int i1 = __float_as_int(f[i].w);
        acc = fmaf(f[i].x, bf2f(vb[(size_t)i0 * NCV]), acc);
        acc = fmaf(f[i].z, bf2f(vb[(size_t)i1 * NCV]), acc);
    }

    __shared__ float tl[64 * 17];
    tl[lane * 17 + wid] = acc;
    __syncthreads();
    if (tid < 256){
        int c = tid >> 2, x4 = (tid & 3) * 4;
        int p0 = blockIdx.x * 16;
        int b0 = p0 / HWSZ; int hw0 = p0 - b0 * HWSZ;
        float4 o = make_float4(tl[c * 17 + x4], tl[c * 17 + x4 + 1],
                               tl[c * 17 + x4 + 2], tl[c * 17 + x4 + 3]);
        *(float4*)(out + ((size_t)b0 * NCV + c) * HWSZ + hw0 + x4) = o;
    }
}

extern "C" void kernel_launch(void* const* d_in, const int* in_sizes, int n_in,
                              void* d_out, int out_size, void* d_ws, size_t ws_size,
                              hipStream_t stream) {
    const float* q   = (const float*)d_in[0];
    const float* v   = (const float*)d_in[1];
    const float* ow1 = (const float*)d_in[2];
    const float* ob1 = (const float*)d_in[3];
    const float* ow2 = (const float*)d_in[4];
    const float* ob2 = (const float*)d_in[5];
    const float* ww1 = (const float*)d_in[6];
    const float* wb1 = (const float*)d_in[7];
    const float* ww2 = (const float*)d_in[8];
    const float* wb2 = (const float*)d_in[9];

    char* ws = (char*)d_ws;
    float*    t1   = (float*)ws;                                   // 150,994,944 B
    uint16_t* whi  = (uint16_t*)(ws + 150994944);                  // 294,912 B
    uint16_t* wlo  = (uint16_t*)(ws + 150994944 + 294912);         // 294,912 B
    const size_t QOFF = 150994944 + 589824;                        // 151,584,768
    const size_t QPL  = (size_t)8 * PP * PP * NCQ * 2;             // 77,078,528 per plane
    uint16_t* qhi  = (uint16_t*)(ws + QOFF);
    uint16_t* qlo  = (uint16_t*)(ws + QOFF + QPL);
    // after K1, the q-split region is dead; alias it:
    uint16_t* vcl  = (uint16_t*)(ws + QOFF);                       // 37,748,736 B
    float2*  sparm = (float2*)  (ws + QOFF + 37748736);            // 37,748,736 B

    float* out = (float*)d_out;

    k0z<<<dim3(8 * PP), dim3(256), 0, stream>>>(qhi, qlo);
    k0w<<<dim3(576), dim3(256), 0, stream>>>(ow1, ww1, whi, wlo);
    k0q<<<dim3(3, 192, 8), dim3(256), 0, stream>>>(q, qhi, qlo);
    k1_conv1_mfma<<<dim3(576, 8), dim3(256), 0, stream>>>(qhi, qlo, whi, wlo, ob1, wb1, t1);
    k2b_vcl<<<dim3(3, 192, 8), dim3(256), 0, stream>>>(v, vcl);
    k2a_prep<<<dim3(144, 8), dim3(256), 0, stream>>>(t1, ow2, ob2, ww2, wb2, sparm);
    k3_gather<<<dim3(18432), dim3(1024), 0, stream>>>(sparm, vcl, out);
}

// Round 4
// 1540.109 us; speedup vs baseline: 1.9722x; 1.1327x over previous
//
#include <hip/hip_runtime.h>
#include <hip/hip_bf16.h>
#include <cmath>

#define HH 192
#define WW 192
#define HWSZ (192*192)
#define NCQ 128
#define NCV 64
#define PP 194          // padded spatial dim (1-px zero border)

typedef __attribute__((ext_vector_type(8))) short short8;
typedef __attribute__((ext_vector_type(4))) float f32x4;

__device__ inline uint16_t f2bf(float x){ __hip_bfloat16 h = __float2bfloat16(x); return *(uint16_t*)&h; }
__device__ inline float bf2f(uint16_t u){ return __uint_as_float(((uint32_t)u)<<16); }

// ---------------------------------------------------------------------------
// K0z: zero the 1-px borders of the padded qhi/qlo planes
// ---------------------------------------------------------------------------
__global__ __launch_bounds__(256) void k0z(uint16_t* __restrict__ qhi, uint16_t* __restrict__ qlo){
    int bi = blockIdx.x; int b = bi / PP; int yP = bi - b * PP;
    size_t rowbase = (((size_t)b * PP + yP) * PP) * NCQ;       // u16 index
    uint32_t* h32 = (uint32_t*)(qhi + rowbase);
    uint32_t* l32 = (uint32_t*)(qlo + rowbase);
    if (yP == 0 || yP == PP-1){
        for (int i = threadIdx.x; i < PP*NCQ/2; i += 256){ h32[i] = 0; l32[i] = 0; }
    } else {
        if (threadIdx.x < 64){ h32[threadIdx.x] = 0; l32[threadIdx.x] = 0; }
        else if (threadIdx.x < 128){ int i = (PP-1)*64 + threadIdx.x - 64; h32[i] = 0; l32[i] = 0; }
    }
}

// ---------------------------------------------------------------------------
// K0w: split conv1 weights to bf16 hi/lo.
// NEW coalesced layout: idx = ((tap*4 + kc)*128 + m)*32 + (ic&31),  kc = ic>>5
//      m<64 -> ow1 branch, m>=64 -> ww1 branch
// ---------------------------------------------------------------------------
__global__ __launch_bounds__(256) void k0w(const float* __restrict__ ow1, const float* __restrict__ ww1,
                                           uint16_t* __restrict__ whi, uint16_t* __restrict__ wlo){
    int d = blockIdx.x * 256 + threadIdx.x;
    if (d >= 128 * 1152) return;
    int m = d / 1152; int r = d - m * 1152; int tap = r >> 7; int ic = r & 127;
    float wv = (m < 64) ? ow1[((size_t)m * NCQ + ic) * 9 + tap]
                        : ww1[((size_t)(m - 64) * NCQ + ic) * 9 + tap];
    uint16_t hi = f2bf(wv);
    uint16_t lo = f2bf(wv - bf2f(hi));
    int dst = ((tap * 4 + (ic >> 5)) * 128 + m) * 32 + (ic & 31);
    whi[dst] = hi; wlo[dst] = lo;
}

// ---------------------------------------------------------------------------
// K0q: q [b][ic][y][x] fp32 -> padded channels-last bf16 hi/lo planes
//      qhi/qlo [b][yP 194][xP 194][ic 128]
// grid (3, 192, 8): x-chunk 64, y, b
// ---------------------------------------------------------------------------
__global__ __launch_bounds__(256) void k0q(const float* __restrict__ q,
                                           uint16_t* __restrict__ qhi, uint16_t* __restrict__ qlo){
    __shared__ uint16_t lh[64 * 136], ll[64 * 136];
    const int x0 = blockIdx.x * 64, y = blockIdx.y, b = blockIdx.z;
    const int t = threadIdx.x;
    const int xr = t & 63;
#pragma unroll 4
    for (int it = 0; it < 32; ++it){
        int ic = it * 4 + (t >> 6);
        float val = q[(((size_t)b * NCQ + ic) * HH + y) * WW + x0 + xr];
        uint16_t hi = f2bf(val);
        uint16_t lo = f2bf(val - bf2f(hi));
        lh[xr * 136 + ic] = hi;
        ll[xr * 136 + ic] = lo;
    }
    __syncthreads();
#pragma unroll
    for (int it = 0; it < 4; ++it){
        int s = t + it * 256;             // 1024 slots: 64 x * 16 ic-chunks
        int x = s >> 4, icb = (s & 15) * 8;
        size_t dst = (((size_t)b * PP + y + 1) * PP + (x0 + x + 1)) * NCQ + icb;
        *(int4*)(qhi + dst) = *(const int4*)(lh + x * 136 + icb);
        *(int4*)(qlo + dst) = *(const int4*)(ll + x * 136 + icb);
    }
}

// ---------------------------------------------------------------------------
// K1: conv1 (both branches, M=128) via split-precision bf16 MFMA + gelu -> t1
// grid (384, 8): strip = bx&1 (96-px half-row), y = bx>>1; 256 thr, 4 waves
// wave tile 64 oc x 48 px (nf=3); block tile 128 oc x 96 px (one row strip)
// ---------------------------------------------------------------------------
__global__ __launch_bounds__(256, 2) void k1_conv1_mfma(
    const uint16_t* __restrict__ qhi, const uint16_t* __restrict__ qlo,
    const uint16_t* __restrict__ whi, const uint16_t* __restrict__ wlo,
    const float* __restrict__ ob1, const float* __restrict__ wb1,
    float* __restrict__ t1)
{
    __shared__ uint16_t qlds[2 * 9408];   // [plane2][row3][col98][ic32] bf16
    const int tid = threadIdx.x;
    const int b = blockIdx.y;
    const int strip = blockIdx.x & 1;
    const int y = blockIdx.x >> 1;
    const int x0 = strip * 96;
    const int lane = tid & 63;
    const int wid = tid >> 6;
    const int wm = wid >> 1;              // oc half (0..1)
    const int wn = wid & 1;               // px half (0..1), 48 px each
    const int l15 = lane & 15;
    const int g = lane >> 4;

    // staging: 2352 16B-chunks (hi 1176 + lo 1176), 10 slots/thread
    // chunk s: plane = s/1176; s2 = s%1176; r = s2/392; c2 = s2%392; c=c2>>2; t3=c2&3
    const uint16_t* ssrc[10]; int slds[10]; bool sok[10];
#pragma unroll
    for (int j = 0; j < 10; ++j){
        int s = tid + j * 256;
        sok[j] = (s < 2352);
        int ss = sok[j] ? s : 0;
        int p = (ss >= 1176) ? 1 : 0;
        int s2 = ss - p * 1176;
        int r = s2 / 392;
        int c2 = s2 - r * 392;
        int c = c2 >> 2;
        int t3 = c2 & 3;
        const uint16_t* base = p ? qlo : qhi;
        ssrc[j] = base + (((size_t)b * PP + y + r) * PP + (x0 + c)) * NCQ + t3 * 8;
        slds[j] = s * 8;                   // LDS element offset (16B chunks linear)
    }

    f32x4 acc[4][3];
#pragma unroll
    for (int mf = 0; mf < 4; ++mf)
#pragma unroll
        for (int nf = 0; nf < 3; ++nf) acc[mf][nf] = (f32x4){0.f,0.f,0.f,0.f};

    // prologue loads for kc=0
    float4 sreg[10];
#pragma unroll
    for (int j = 0; j < 10; ++j) if (sok[j]) sreg[j] = *(const float4*)(ssrc[j]);

    for (int kc = 0; kc < 4; ++kc){
        __syncthreads();                  // previous compute done with LDS
#pragma unroll
        for (int j = 0; j < 10; ++j) if (sok[j]) *(float4*)(&qlds[slds[j]]) = sreg[j];
        __syncthreads();
        if (kc < 3){
#pragma unroll
            for (int j = 0; j < 10; ++j) if (sok[j]) sreg[j] = *(const float4*)(ssrc[j] + (kc + 1) * 32);
        }
#pragma unroll
        for (int tap = 0; tap < 9; ++tap){
            const int dy = tap / 3, dx = tap % 3;
            short8 bh[3], bl[3];
#pragma unroll
            for (int nf = 0; nf < 3; ++nf){
                int c = wn * 48 + nf * 16 + l15 + dx;
                int off = (dy * 98 + c) * 32 + 8 * g;
                bh[nf] = *(const short8*)(&qlds[off]);
                bl[nf] = *(const short8*)(&qlds[9408 + off]);
            }
#pragma unroll
            for (int mf = 0; mf < 4; ++mf){
                // coalesced weight fragment: contiguous 1KB per wave-instruction
                size_t wo = ((size_t)(tap * 4 + kc) * 128 + wm * 64 + mf * 16 + l15) * 32 + 8 * g;
                short8 ah = *(const short8*)(whi + wo);
                short8 al = *(const short8*)(wlo + wo);
#pragma unroll
                for (int nf = 0; nf < 3; ++nf){
                    acc[mf][nf] = __builtin_amdgcn_mfma_f32_16x16x32_bf16(ah, bh[nf], acc[mf][nf], 0, 0, 0);
                    acc[mf][nf] = __builtin_amdgcn_mfma_f32_16x16x32_bf16(ah, bl[nf], acc[mf][nf], 0, 0, 0);
                    acc[mf][nf] = __builtin_amdgcn_mfma_f32_16x16x32_bf16(al, bh[nf], acc[mf][nf], 0, 0, 0);
                }
            }
        }
    }

    // epilogue: bias + exact gelu + store
    const float* bias = wm ? wb1 : ob1;
#pragma unroll
    for (int mf = 0; mf < 4; ++mf){
#pragma unroll
        for (int nf = 0; nf < 3; ++nf){
#pragma unroll
            for (int qq = 0; qq < 4; ++qq){
                int ocl = mf * 16 + g * 4 + qq;
                float xv = acc[mf][nf][qq] + bias[ocl];
                float ge = 0.5f * xv * (1.0f + erff(xv * 0.70710678118654752f));
                int oc = wm * 64 + ocl;
                int x = x0 + wn * 48 + nf * 16 + l15;
                t1[(((size_t)b * NCQ + oc) * HH + y) * WW + x] = ge;
            }
        }
    }
}

// ---------------------------------------------------------------------------
// K2b: v [b][c][y][x] fp32 -> vcl [b][y][x][c] bf16 (channels-last)
// grid (3, 192, 8)
// ---------------------------------------------------------------------------
__global__ __launch_bounds__(256) void k2b_vcl(const float* __restrict__ v, uint16_t* __restrict__ vcl){
    __shared__ uint16_t tl[64 * 72];
    const int x0 = blockIdx.x * 64, y = blockIdx.y, b = blockIdx.z;
    const int t = threadIdx.x;
    const int xr = t & 63;
#pragma unroll 4
    for (int it = 0; it < 16; ++it){
        int c = it * 4 + (t >> 6);
        float val = v[(((size_t)b * NCV + c) * HH + y) * WW + x0 + xr];
        tl[xr * 72 + c] = f2bf(val);
    }
    __syncthreads();
#pragma unroll
    for (int it = 0; it < 2; ++it){
        int s = t + it * 256;             // 512 slots: 64 x * 8 c-chunks
        int x = s >> 3, cb = (s & 7) * 8;
        size_t dst = ((size_t)b * HWSZ + (size_t)y * WW + x0 + x) * NCV + cb;
        *(int4*)(vcl + dst) = *(const int4*)(tl + x * 72 + cb);
    }
}

// ---------------------------------------------------------------------------
// K2a: conv2 (12 out ch) + bias + softmax + sample-coeff prep -> sparm
// grid (144, 8), block 256, 1 px/thread (16x16 tiles)
// ---------------------------------------------------------------------------
__global__ __launch_bounds__(256) void k2a_prep(
    const float* __restrict__ t1,
    const float* __restrict__ ow2, const float* __restrict__ ob2,
    const float* __restrict__ ww2, const float* __restrict__ wb2,
    float2* __restrict__ sparm)
{
    __shared__ float lds[16 * 360];
    const int tid = threadIdx.x;
    const int b   = blockIdx.y;
    const int ty0 = (blockIdx.x / 12) << 4;
    const int tx0 = (blockIdx.x % 12) << 4;

    int  sgoff[2], slds2[2];
    bool swr[2], sok2[2];
#pragma unroll
    for (int j = 0; j < 2; ++j){
        const int i = tid + j * 256;
        const int r = i / 18;
        const int c = i - r * 18;
        const int gy = ty0 - 1 + r;
        const int gx = tx0 - 1 + c;
        swr[j]   = (i < 324);
        sok2[j]  = swr[j] && (gy >= 0) && (gy < HH) && (gx >= 0) && (gx < WW);
        sgoff[j] = gy * WW + gx;
        slds2[j] = r * 20 + c;
    }
    const float* tb = t1 + (size_t)b * NCQ * HWSZ;

    float acc[12];
#pragma unroll
    for (int i = 0; i < 12; ++i) acc[i] = 0.f;

    const int ty = tid >> 4, tx = tid & 15;

    for (int cb = 0; cb < 64; cb += 8){
        __syncthreads();
#pragma unroll
        for (int p = 0; p < 16; ++p){
            const int ch = (p < 8) ? (cb + p) : (64 + cb + (p - 8));
            const float* tp = tb + (size_t)ch * HWSZ;
#pragma unroll
            for (int j = 0; j < 2; ++j)
                if (swr[j]) lds[p * 360 + slds2[j]] = sok2[j] ? tp[sgoff[j]] : 0.f;
        }
        __syncthreads();
#pragma unroll
        for (int p = 0; p < 8; ++p){
            float win[3][3];
#pragma unroll
            for (int r = 0; r < 3; ++r)
#pragma unroll
                for (int c = 0; c < 3; ++c)
                    win[r][c] = lds[p * 360 + (ty + r) * 20 + (tx + c)];
            const float* wo = ow2 + (cb + p) * 9;
#pragma unroll
            for (int oc = 0; oc < 8; ++oc)
#pragma unroll
                for (int t = 0; t < 9; ++t)
                    acc[oc] = fmaf(wo[oc * 576 + t], win[t / 3][t % 3], acc[oc]);

            float win2[3][3];
#pragma unroll
            for (int r = 0; r < 3; ++r)
#pragma unroll
                for (int c = 0; c < 3; ++c)
                    win2[r][c] = lds[(p + 8) * 360 + (ty + r) * 20 + (tx + c)];
            const float* wl = ww2 + (cb + p) * 9;
#pragma unroll
            for (int oc = 0; oc < 4; ++oc)
#pragma unroll
                for (int t = 0; t < 9; ++t)
                    acc[8 + oc] = fmaf(wl[oc * 576 + t], win2[t / 3][t % 3], acc[8 + oc]);
        }
    }

    const int y = ty0 + ty, x = tx0 + tx;

    float offv[8];
#pragma unroll
    for (int i = 0; i < 8; ++i) offv[i] = acc[i] + ob2[i];
    float lg[4];
#pragma unroll
    for (int i = 0; i < 4; ++i) lg[i] = acc[8 + i] + wb2[i];

    const float m = fmaxf(fmaxf(lg[0], lg[1]), fmaxf(lg[2], lg[3]));
    float e[4], s = 0.f;
#pragma unroll
    for (int i = 0; i < 4; ++i){ e[i] = expf(lg[i] - m); s += e[i]; }
    const float sinv = 1.f / s;

    float2 pr[16];
#pragma unroll
    for (int k = 0; k < 4; ++k){
        const float wk = e[k] * sinv;
        const float px = (float)x + offv[2 * k]     * (0.5f * (WW - 1));
        const float py = (float)y + offv[2 * k + 1] * (0.5f * (HH - 1));
        const float fx0 = floorf(px), fy0 = floorf(py);
        const float wx1 = px - fx0, wx0f = 1.f - wx1;
        const float wy1 = py - fy0, wy0f = 1.f - wy1;
#pragma unroll
        for (int cy = 0; cy < 2; ++cy)
#pragma unroll
            for (int cx = 0; cx < 2; ++cx){
                const float fx = fx0 + (float)cx;
                const float fy = fy0 + (float)cy;
                const bool ok = (fx >= 0.f) && (fx <= (float)(WW - 1)) &&
                                (fy >= 0.f) && (fy <= (float)(HH - 1));
                const int xi = (int)fminf(fmaxf(fx, 0.f), (float)(WW - 1));
                const int yi = (int)fminf(fmaxf(fy, 0.f), (float)(HH - 1));
                const float wgt = (cx ? wx1 : wx0f) * (cy ? wy1 : wy0f) * wk;
                pr[k * 4 + cy * 2 + cx] = make_float2(ok ? wgt : 0.f,
                                                      __int_as_float(yi * WW + xi));
            }
    }
    float2* sp = sparm + ((size_t)b * HWSZ + (size_t)y * WW + x) * 16;
#pragma unroll
    for (int i = 0; i < 16; ++i) sp[i] = pr[i];
}

// ---------------------------------------------------------------------------
// K3: gather + weighted sum. 1 wave per pixel (lane = channel), 16 px/block.
// grid 18432, block 1024
// ---------------------------------------------------------------------------
__global__ __launch_bounds__(1024) void k3_gather(
    const float2* __restrict__ sparm, const uint16_t* __restrict__ vcl,
    float* __restrict__ out)
{
    const int tid = threadIdx.x;
    const int wid = tid >> 6, lane = tid & 63;
    const int p = blockIdx.x * 16 + wid;
    const int b = p / HWSZ;

    const float4* s4 = (const float4*)(sparm + (size_t)p * 16);
    float4 f[8];
#pragma unroll
    for (int i = 0; i < 8; ++i) f[i] = s4[i];

    const uint16_t* vb = vcl + (size_t)b * HWSZ * NCV + lane;
    float acc = 0.f;
#pragma unroll
    for (int i = 0; i < 8; ++i){
        int i0 = __float_as_int(f[i].y);
        int i1 = __float_as_int(f[i].w);
        acc = fmaf(f[i].x, bf2f(vb[(size_t)i0 * NCV]), acc);
        acc = fmaf(f[i].z, bf2f(vb[(size_t)i1 * NCV]), acc);
    }

    __shared__ float tl[64 * 17];
    tl[lane * 17 + wid] = acc;
    __syncthreads();
    if (tid < 256){
        int c = tid >> 2, x4 = (tid & 3) * 4;
        int p0 = blockIdx.x * 16;
        int b0 = p0 / HWSZ; int hw0 = p0 - b0 * HWSZ;
        float4 o = make_float4(tl[c * 17 + x4], tl[c * 17 + x4 + 1],
                               tl[c * 17 + x4 + 2], tl[c * 17 + x4 + 3]);
        *(float4*)(out + ((size_t)b0 * NCV + c) * HWSZ + hw0 + x4) = o;
    }
}

extern "C" void kernel_launch(void* const* d_in, const int* in_sizes, int n_in,
                              void* d_out, int out_size, void* d_ws, size_t ws_size,
                              hipStream_t stream) {
    const float* q   = (const float*)d_in[0];
    const float* v   = (const float*)d_in[1];
    const float* ow1 = (const float*)d_in[2];
    const float* ob1 = (const float*)d_in[3];
    const float* ow2 = (const float*)d_in[4];
    const float* ob2 = (const float*)d_in[5];
    const float* ww1 = (const float*)d_in[6];
    const float* wb1 = (const float*)d_in[7];
    const float* ww2 = (const float*)d_in[8];
    const float* wb2 = (const float*)d_in[9];

    char* ws = (char*)d_ws;
    float*    t1   = (float*)ws;                                   // 150,994,944 B
    uint16_t* whi  = (uint16_t*)(ws + 150994944);                  // 294,912 B
    uint16_t* wlo  = (uint16_t*)(ws + 150994944 + 294912);         // 294,912 B
    const size_t QOFF = 150994944 + 589824;                        // 151,584,768
    const size_t QPL  = (size_t)8 * PP * PP * NCQ * 2;             // 77,078,528 per plane
    uint16_t* qhi  = (uint16_t*)(ws + QOFF);
    uint16_t* qlo  = (uint16_t*)(ws + QOFF + QPL);
    // after K1, the q-split region is dead; alias it:
    uint16_t* vcl  = (uint16_t*)(ws + QOFF);                       // 37,748,736 B
    float2*  sparm = (float2*)  (ws + QOFF + 37748736);            // 37,748,736 B

    float* out = (float*)d_out;

    k0z<<<dim3(8 * PP), dim3(256), 0, stream>>>(qhi, qlo);
    k0w<<<dim3(576), dim3(256), 0, stream>>>(ow1, ww1, whi, wlo);
    k0q<<<dim3(3, 192, 8), dim3(256), 0, stream>>>(q, qhi, qlo);
    k1_conv1_mfma<<<dim3(384, 8), dim3(256), 0, stream>>>(qhi, qlo, whi, wlo, ob1, wb1, t1);
    k2b_vcl<<<dim3(3, 192, 8), dim3(256), 0, stream>>>(v, vcl);
    k2a_prep<<<dim3(144, 8), dim3(256), 0, stream>>>(t1, ow2, ob2, ww2, wb2, sparm);
    k3_gather<<<dim3(18432), dim3(1024), 0, stream>>>(sparm, vcl, out);
}